// Round 13
// baseline (996.581 us; speedup 1.0000x reference)
//
#include <hip/hip_runtime.h>

// LightGCN on MI355X — round 23.
//  * R22 forensics: absmax error (6.5e-4) == inferred max|ref| -> output
//    stayed zero -> hipLaunchCooperativeKernel silently failed under graph
//    capture. Fusion logic never ran.
//  * Same 6-phase fusion, NO cooperative API: software grid barrier
//    (monotonic agent-scope atomic counter, threadfence release/acquire,
//    s_sleep spin). Co-residency by construction: GRID=768=3 blocks/CU,
//    LDS 47104x3=141KB<=160KB, launch_bounds(256,3) (VGPR cap ~170 >>
//    ~90 needed). Barrier counter zeroed by the same hipMemsetAsync as
//    tcur (kernel-boundary coherence). 2 launches: memset, fused.
//  * Phase bodies byte-equivalent to R21's proven kernels.

#define DIM 64
#define TSHIFT 8
#define TMASK ((1 << TSHIFT) - 1)
#define TPAD 768
#define EWG 6272
#define STAGE_CAP 6272
#define NREP 4
#define RSTR 2560
#define TSTRIDE 10240
#define NI4 7  // ceil((EWG/4)/256) int4 slots per thread
#define GRID 768

typedef unsigned short u16;
typedef unsigned char u8;
typedef unsigned int u32;
typedef unsigned int uv4 __attribute__((ext_vector_type(4)));
typedef float f2 __attribute__((ext_vector_type(2)));

__device__ __forceinline__ u32 f2bf(float f) {  // RNE pack to bf16 bits
  u32 u = __float_as_uint(f);
  return (u + 0x7FFFu + ((u >> 16) & 1u)) >> 16;
}
__device__ __forceinline__ float bflo(u32 u) {
  return __uint_as_float(u << 16);
}
__device__ __forceinline__ float bfhi(u32 u) {
  return __uint_as_float(u & 0xFFFF0000u);
}
__device__ __forceinline__ f2 up2(u32 u) {
  f2 r;
  r.x = bflo(u);
  r.y = bfhi(u);
  return r;
}

// phase-overlaid shared memory (max = partition's 46864 B)
union SM {
  struct {
    u32 sorted[STAGE_CAP];
    u16 sortedt[STAGE_CAP];
    int cnt[TPAD], lstart[TPAD], gbase[TPAD], wsum[4];
  } part;
  struct {
    int tl[TPAD], hist[256], cur[256], wsum[4];
  } bld;
  struct {
    float ab[2][2][64];
  } sc;
};

// software grid barrier: monotonic counter (zeroed per replay by memset).
// release fence -> arrive -> spin to target -> acquire fence.
__device__ __forceinline__ void grid_barrier(int* g_arrive, int target) {
  __syncthreads();
  if (threadIdx.x == 0) {
    __threadfence();  // agent release: flush this XCD's dirty lines
    __hip_atomic_fetch_add(g_arrive, 1, __ATOMIC_ACQ_REL,
                           __HIP_MEMORY_SCOPE_AGENT);
    while (__hip_atomic_load(g_arrive, __ATOMIC_ACQUIRE,
                             __HIP_MEMORY_SCOPE_AGENT) < target)
      __builtin_amdgcn_s_sleep(8);
    __threadfence();  // agent acquire: invalidate stale cached lines
  }
  __syncthreads();
}

// inclusive scan of lsum across 256 threads; wsum is 4-entry LDS scratch.
__device__ __forceinline__ int block_incl_scan(int lsum, int tid, int* wsum) {
  int lane = tid & 63, wv = tid >> 6;
  int v = lsum;
#pragma unroll
  for (int off = 1; off < 64; off <<= 1) {
    int t = __shfl_up(v, off, 64);
    if (lane >= off) v += t;
  }
  __syncthreads();
  if (lane == 63) wsum[wv] = v;
  __syncthreads();
  int add = 0;
  if (wv > 0) add += wsum[0];
  if (wv > 1) add += wsum[1];
  if (wv > 2) add += wsum[2];
  return v + add;
}

// ---------------- SpMM body: 1 row / 8-lane group, 2-stage pipeline --------

__device__ __forceinline__ void load_stage(
    u32 (&c)[8], uv4 (&g)[8], int k, int d, int s,
    const u32* __restrict__ csr, const char* __restrict__ yb, u32 soff,
    int n) {
#pragma unroll
  for (int j = 0; j < 8; ++j) c[j] = (k + j < d) ? csr[s + k + j] : (u32)n;
#pragma unroll
  for (int j = 0; j < 8; ++j)
    g[j] = *(const uv4*)(yb + (size_t)(((size_t)c[j] << 7) | soff));
}

#define ACC_STAGE(G)                                                         \
  _Pragma("unroll") for (int j = 0; j < 8; ++j) {                            \
    a0 += up2(G[j].x);                                                       \
    a1 += up2(G[j].y);                                                       \
    a2 += up2(G[j].z);                                                       \
    a3 += up2(G[j].w);                                                       \
  }

__device__ void spmm_phase(const int* __restrict__ row_ptr,
                           const u32* __restrict__ csr,
                           const u16* __restrict__ yin,
                           u16* __restrict__ yout, int n, int sblocks) {
  if (blockIdx.x == 0 && threadIdx.x < 8)  // zero sentinel row of output
    ((uint4*)(yout + (size_t)n * DIM))[threadIdx.x] = make_uint4(0, 0, 0, 0);
  for (int vb = blockIdx.x; vb < sblocks; vb += GRID) {
    int row = (vb * 256 + threadIdx.x) >> 3;
    int q8 = threadIdx.x & 7;
    if (row >= n) continue;
    int s = row_ptr[row];
    int d = row_ptr[row + 1] - s;
    const char* yb = (const char*)yin;
    u32 soff = (u32)q8 << 4;
    f2 a0 = 0.f, a1 = 0.f, a2 = 0.f, a3 = 0.f;
    u32 cA[8], cB[8];
    uv4 gA[8], gB[8];
    if (d > 0) {
      load_stage(cA, gA, 0, d, s, csr, yb, soff, n);
      int k = 8;
      while (k < d) {
        load_stage(cB, gB, k, d, s, csr, yb, soff, n);
        k += 8;
        ACC_STAGE(gA)
        if (k >= d) {
          ACC_STAGE(gB)
          goto done;
        }
        load_stage(cA, gA, k, d, s, csr, yb, soff, n);
        k += 8;
        ACC_STAGE(gB)
      }
      ACC_STAGE(gA)
    }
  done:;
    float inv = 1.0f / (float)max(d, 1);
    uint4 o;
    o.x = f2bf(a0.x * inv) | (f2bf(a0.y * inv) << 16);
    o.y = f2bf(a1.x * inv) | (f2bf(a1.y * inv) << 16);
    o.z = f2bf(a2.x * inv) | (f2bf(a2.y * inv) << 16);
    o.w = f2bf(a3.x * inv) | (f2bf(a3.y * inv) << 16);
    ((uint4*)(yout + (size_t)row * DIM))[q8] = o;
  }
}

// ---------------- scorer gather (register-only) ----------------------------

#define ACC8(G)                                                              \
  s0 += bflo(G.x); s1 += bfhi(G.x);                                          \
  s2 += bflo(G.y); s3 += bfhi(G.y);                                          \
  s4 += bflo(G.z); s5 += bfhi(G.z);                                          \
  s6 += bflo(G.w); s7 += bfhi(G.w);

__device__ __forceinline__ void gather8(
    const int* __restrict__ row_ptr, const u32* __restrict__ csr,
    const u16* __restrict__ y, int row, int s, int q8, int n, float* o) {
  int start = row_ptr[row];
  int end = row_ptr[row + 1];
  float s0 = 0.f, s1 = 0.f, s2 = 0.f, s3 = 0.f;
  float s4 = 0.f, s5 = 0.f, s6 = 0.f, s7 = 0.f;
  for (int k = start + s; k < end; k += 16) {
    int k2 = k + 8;
    bool ok2 = k2 < end;
    u32 c0 = csr[k];
    u32 c1 = ok2 ? csr[k2] : (u32)n;
    uint4 g0 = ((const uint4*)(y + (size_t)c0 * DIM))[q8];
    uint4 g1 = ((const uint4*)(y + (size_t)c1 * DIM))[q8];
    ACC8(g0) ACC8(g1)
  }
  for (int m = 8; m <= 32; m <<= 1) {
    s0 += __shfl_xor(s0, m, 64); s1 += __shfl_xor(s1, m, 64);
    s2 += __shfl_xor(s2, m, 64); s3 += __shfl_xor(s3, m, 64);
    s4 += __shfl_xor(s4, m, 64); s5 += __shfl_xor(s5, m, 64);
    s6 += __shfl_xor(s6, m, 64); s7 += __shfl_xor(s7, m, 64);
  }
  o[0] = s0; o[1] = s1; o[2] = s2; o[3] = s3;
  o[4] = s4; o[5] = s5; o[6] = s6; o[7] = s7;
}

// ---------------- the fused pipeline ---------------------------------------

__global__ __launch_bounds__(256, 3) void lightgcn_fused(
    const int* __restrict__ rows, const int* __restrict__ cols, int nnz,
    int T, int npw, const float4* __restrict__ ue,
    const float4* __restrict__ ie, const int* __restrict__ user_ids,
    const int* __restrict__ item_ids, int U, int N, int B,
    int* __restrict__ tcur, int* g_arrive, u32* __restrict__ bucket,
    int* __restrict__ row_ptr, u32* __restrict__ csr, u16* __restrict__ y0b,
    u16* __restrict__ y1b, u16* __restrict__ y2b, float* __restrict__ out) {
  __shared__ SM sm;
  int tid = threadIdx.x;

  // ---- P1: partition into padded tile bucket -------------------------
  {
    int w = blockIdx.x;
    if (w < npw) {
      int rep = w & (NREP - 1);
      int j0 = tid * 3;
      sm.part.cnt[j0] = 0; sm.part.cnt[j0 + 1] = 0; sm.part.cnt[j0 + 2] = 0;
      __syncthreads();
      int base = w * EWG;
      int end = min(base + EWG, nnz);
      int total = end - base;
      int nv = total >> 2;
      const int4* r4 = (const int4*)(rows + base);
      const int4* c4 = (const int4*)(cols + base);
      int4 rr[NI4];
#pragma unroll
      for (int j = 0; j < NI4; ++j) {
        int i = tid + j * 256;
        if (i < nv) {
          int4 r = r4[i];
          rr[j] = r;
          atomicAdd(&sm.part.cnt[r.x >> TSHIFT], 1);
          atomicAdd(&sm.part.cnt[r.y >> TSHIFT], 1);
          atomicAdd(&sm.part.cnt[r.z >> TSHIFT], 1);
          atomicAdd(&sm.part.cnt[r.w >> TSHIFT], 1);
        }
      }
      for (int e = base + (nv << 2) + tid; e < end; e += 256)
        atomicAdd(&sm.part.cnt[rows[e] >> TSHIFT], 1);
      __syncthreads();
      int c0 = sm.part.cnt[j0], c1 = sm.part.cnt[j0 + 1],
          c2 = sm.part.cnt[j0 + 2];
      int lsum = c0 + c1 + c2;
      int incl = block_incl_scan(lsum, tid, sm.part.wsum);
      int excl = incl - lsum;
      sm.part.lstart[j0] = excl;
      sm.part.lstart[j0 + 1] = excl + c0;
      sm.part.lstart[j0 + 2] = excl + c0 + c1;
      if (c0 > 0)
        sm.part.gbase[j0] = j0 * TSTRIDE + rep * RSTR +
                            atomicAdd(&tcur[j0 * NREP + rep], c0);
      if (c1 > 0)
        sm.part.gbase[j0 + 1] = (j0 + 1) * TSTRIDE + rep * RSTR +
                                atomicAdd(&tcur[(j0 + 1) * NREP + rep], c1);
      if (c2 > 0)
        sm.part.gbase[j0 + 2] = (j0 + 2) * TSTRIDE + rep * RSTR +
                                atomicAdd(&tcur[(j0 + 2) * NREP + rep], c2);
      sm.part.cnt[j0] = 0; sm.part.cnt[j0 + 1] = 0; sm.part.cnt[j0 + 2] = 0;
      __syncthreads();
#pragma unroll
      for (int j = 0; j < NI4; ++j) {
        int i = tid + j * 256;
        if (i < nv) {
          int4 r = rr[j];
          int4 c = c4[i];
          int t, s, d;
          t = r.x >> TSHIFT; s = atomicAdd(&sm.part.cnt[t], 1);
          d = sm.part.lstart[t] + s;
          sm.part.sorted[d] = ((u32)(r.x & TMASK) << 18) | (u32)c.x;
          sm.part.sortedt[d] = (u16)t;
          t = r.y >> TSHIFT; s = atomicAdd(&sm.part.cnt[t], 1);
          d = sm.part.lstart[t] + s;
          sm.part.sorted[d] = ((u32)(r.y & TMASK) << 18) | (u32)c.y;
          sm.part.sortedt[d] = (u16)t;
          t = r.z >> TSHIFT; s = atomicAdd(&sm.part.cnt[t], 1);
          d = sm.part.lstart[t] + s;
          sm.part.sorted[d] = ((u32)(r.z & TMASK) << 18) | (u32)c.z;
          sm.part.sortedt[d] = (u16)t;
          t = r.w >> TSHIFT; s = atomicAdd(&sm.part.cnt[t], 1);
          d = sm.part.lstart[t] + s;
          sm.part.sorted[d] = ((u32)(r.w & TMASK) << 18) | (u32)c.w;
          sm.part.sortedt[d] = (u16)t;
        }
      }
      for (int e = base + (nv << 2) + tid; e < end; e += 256) {
        int r = rows[e];
        int c = cols[e];
        int t = r >> TSHIFT;
        int s = atomicAdd(&sm.part.cnt[t], 1);
        int d = sm.part.lstart[t] + s;
        sm.part.sorted[d] = ((u32)(r & TMASK) << 18) | (u32)c;
        sm.part.sortedt[d] = (u16)t;
      }
      __syncthreads();
      for (int i = tid; i < total; i += 256) {
        int t = sm.part.sortedt[i];
        bucket[(size_t)sm.part.gbase[t] + (i - sm.part.lstart[t])] =
            sm.part.sorted[i];
      }
    }
  }
  grid_barrier(g_arrive, GRID);

  // ---- P2: build row_ptr + compact csr + fused bf16 y0 ---------------
  {
    int b = blockIdx.x;
    if (b < T) {
      int t = (b & 1) ? (T - 1 - (b >> 1)) : (b >> 1);
      int j0 = tid * 3;
      int v0 = 0, v1 = 0, v2 = 0;
      if (j0 < T) {
        int4 q = ((const int4*)tcur)[j0];
        v0 = q.x + q.y + q.z + q.w;
      }
      if (j0 + 1 < T) {
        int4 q = ((const int4*)tcur)[j0 + 1];
        v1 = q.x + q.y + q.z + q.w;
      }
      if (j0 + 2 < T) {
        int4 q = ((const int4*)tcur)[j0 + 2];
        v2 = q.x + q.y + q.z + q.w;
      }
      int lsum = v0 + v1 + v2;
      int incl0 = block_incl_scan(lsum, tid, sm.bld.wsum);
      int excl0 = incl0 - lsum;
      sm.bld.tl[j0] = excl0 + v0;
      sm.bld.tl[j0 + 1] = excl0 + v0 + v1;
      sm.bld.tl[j0 + 2] = excl0 + v0 + v1 + v2;
      sm.bld.hist[tid] = 0;
      __syncthreads();
      int tbase = (t == 0) ? 0 : sm.bld.tl[t - 1];
      int4 rl = ((const int4*)tcur)[t];
#pragma unroll
      for (int rep = 0; rep < NREP; ++rep) {
        int len =
            (rep == 0) ? rl.x : (rep == 1) ? rl.y : (rep == 2) ? rl.z : rl.w;
        int rs = t * TSTRIDE + rep * RSTR;
        const uint4* b4 = (const uint4*)(bucket + rs);
        int nv = len >> 2;
        for (int i = tid; i < nv; i += 256) {
          uint4 e = b4[i];
          atomicAdd(&sm.bld.hist[e.x >> 18], 1);
          atomicAdd(&sm.bld.hist[e.y >> 18], 1);
          atomicAdd(&sm.bld.hist[e.z >> 18], 1);
          atomicAdd(&sm.bld.hist[e.w >> 18], 1);
        }
        for (int i = rs + (nv << 2) + tid; i < rs + len; i += 256)
          atomicAdd(&sm.bld.hist[bucket[i] >> 18], 1);
      }
      __syncthreads();
      int h = sm.bld.hist[tid];
      int incl = block_incl_scan(h, tid, sm.bld.wsum);
      int r = (t << TSHIFT) + tid;
      if (r < N) row_ptr[r + 1] = tbase + incl;
      if (t == 0 && tid == 0) row_ptr[0] = 0;
      if (b == 0 && tid < 8)  // zero sentinel row of y0 (spmm1 pads with it)
        ((uint4*)y0b)[(size_t)N * 8 + tid] = make_uint4(0, 0, 0, 0);
      sm.bld.cur[tid] = tbase + incl - h;
      __syncthreads();
      for (int pass = 0; pass < 8; ++pass) {
        int lr = pass * 32 + (tid >> 3);
        int q = tid & 7;
        int row = (t << TSHIFT) + lr;
        if (row < N) {
          float invs = rsqrtf((float)max(sm.bld.hist[lr], 1));
          const float4* src = (row < U)
                                  ? (ue + (size_t)row * 16 + q * 2)
                                  : (ie + (size_t)(row - U) * 16 + q * 2);
          float4 a = src[0], bb = src[1];
          uint4 o;
          o.x = f2bf(a.x * invs) | (f2bf(a.y * invs) << 16);
          o.y = f2bf(a.z * invs) | (f2bf(a.w * invs) << 16);
          o.z = f2bf(bb.x * invs) | (f2bf(bb.y * invs) << 16);
          o.w = f2bf(bb.z * invs) | (f2bf(bb.w * invs) << 16);
          ((uint4*)y0b)[(size_t)row * 8 + q] = o;
        }
      }
#pragma unroll
      for (int rep = 0; rep < NREP; ++rep) {
        int len =
            (rep == 0) ? rl.x : (rep == 1) ? rl.y : (rep == 2) ? rl.z : rl.w;
        int rs = t * TSTRIDE + rep * RSTR;
        const uint4* b4 = (const uint4*)(bucket + rs);
        int nv = len >> 2;
        for (int i = tid; i < nv; i += 256) {
          uint4 e = b4[i];
          csr[atomicAdd(&sm.bld.cur[e.x >> 18], 1)] = e.x & 0x3FFFFu;
          csr[atomicAdd(&sm.bld.cur[e.y >> 18], 1)] = e.y & 0x3FFFFu;
          csr[atomicAdd(&sm.bld.cur[e.z >> 18], 1)] = e.z & 0x3FFFFu;
          csr[atomicAdd(&sm.bld.cur[e.w >> 18], 1)] = e.w & 0x3FFFFu;
        }
        for (int i = rs + (nv << 2) + tid; i < rs + len; i += 256) {
          u32 e = bucket[i];
          csr[atomicAdd(&sm.bld.cur[e >> 18], 1)] = e & 0x3FFFFu;
        }
      }
    }
  }
  grid_barrier(g_arrive, 2 * GRID);

  // ---- P3 + P4: two SpMM layers --------------------------------------
  const int sblocks = (N * 8 + 255) / 256;
  spmm_phase(row_ptr, csr, y0b, y1b, N, sblocks);
  grid_barrier(g_arrive, 3 * GRID);
  spmm_phase(row_ptr, csr, y1b, y2b, N, sblocks);
  grid_barrier(g_arrive, 4 * GRID);

  // ---- P5: fused layer-3 + scorer ------------------------------------
  {
    int pairs = (B + 1) / 2;
    int pl = tid >> 7;          // pair slot in block (0,1)
    int side = (tid >> 6) & 1;  // 0=user, 1=item
    int lane = tid & 63;
    int s = lane >> 3;
    int q8 = lane & 7;
    for (int vb = blockIdx.x; vb < pairs; vb += GRID) {
      int w = vb * 2 + pl;
      bool active = w < B;
      if (active) {
        int u = user_ids[w];
        int iti = item_ids[w];
        int row = (side == 0) ? u : iti + U;
        float g[8];
        gather8(row_ptr, csr, y2b, row, s, q8, N, g);
        int dd = row_ptr[row + 1] - row_ptr[row];
        float sd = sqrtf((float)max(dd, 1)), rd = 1.0f / sd;
        const float4* pe = (side == 0) ? ue + (size_t)u * 16 + q8 * 2
                                       : ie + (size_t)iti * 16 + q8 * 2;
        float4 ea = pe[0], eb = pe[1];
        uint4 y1v = ((const uint4*)y1b)[(size_t)row * 8 + q8];
        uint4 y2v = ((const uint4*)y2b)[(size_t)row * 8 + q8];
        if (s == 0) {  // one writer per q8 (all s-lanes hold identical g)
          float* dst = &sm.sc.ab[pl][side][q8 * 8];
          dst[0] = ea.x + sd * (bflo(y1v.x) + bflo(y2v.x)) + rd * g[0];
          dst[1] = ea.y + sd * (bfhi(y1v.x) + bfhi(y2v.x)) + rd * g[1];
          dst[2] = ea.z + sd * (bflo(y1v.y) + bflo(y2v.y)) + rd * g[2];
          dst[3] = ea.w + sd * (bfhi(y1v.y) + bfhi(y2v.y)) + rd * g[3];
          dst[4] = eb.x + sd * (bflo(y1v.z) + bflo(y2v.z)) + rd * g[4];
          dst[5] = eb.y + sd * (bfhi(y1v.z) + bfhi(y2v.z)) + rd * g[5];
          dst[6] = eb.z + sd * (bflo(y1v.w) + bflo(y2v.w)) + rd * g[6];
          dst[7] = eb.w + sd * (bfhi(y1v.w) + bfhi(y2v.w)) + rd * g[7];
        }
      }
      __syncthreads();
      if (active && side == 0) {
        float p = sm.sc.ab[pl][0][lane] * sm.sc.ab[pl][1][lane];
        p += __shfl_xor(p, 1, 64);
        p += __shfl_xor(p, 2, 64);
        p += __shfl_xor(p, 4, 64);
        p += __shfl_xor(p, 8, 64);
        p += __shfl_xor(p, 16, 64);
        p += __shfl_xor(p, 32, 64);
        if (lane == 0) out[w] = p * (1.0f / 16.0f);
      }
      __syncthreads();
    }
  }
}

extern "C" void kernel_launch(void* const* d_in, const int* in_sizes, int n_in,
                              void* d_out, int out_size, void* d_ws, size_t ws_size,
                              hipStream_t stream) {
  const int* adj_rows = (const int*)d_in[3];
  const int* adj_cols = (const int*)d_in[4];
  const int* user_ids = (const int*)d_in[5];
  const int* item_ids = (const int*)d_in[6];

  int U = in_sizes[0] / DIM;  // 100000
  int I = in_sizes[1] / DIM;  // 50000
  int N = U + I;              // 150000
  int nnz = in_sizes[2];      // 3200000
  int B = in_sizes[5];        // 4096

  int T = (N + TMASK) >> TSHIFT;    // 586
  int npw = (nnz + EWG - 1) / EWG;  // 511

  char* p = (char*)d_ws;
  auto carve = [&](size_t bytes) {
    void* r = (void*)p;
    p += (bytes + 255) & ~(size_t)255;
    return r;
  };
  u16* y0b = (u16*)carve((size_t)(N + 1) * DIM * 2);
  u16* y1b = (u16*)carve((size_t)(N + 1) * DIM * 2);
  u16* y2b = (u16*)carve((size_t)(N + 1) * DIM * 2);
  int* row_ptr = (int*)carve((size_t)(N + 1) * 4);
  int* ctrl = (int*)carve(((size_t)T * NREP + 64) * 4);  // tcur + barrier
  u32* bucket = (u32*)carve((size_t)(T + 1) * TSTRIDE * 4);
  u32* csr = (u32*)carve((size_t)nnz * 4);

  int* tcur = ctrl;
  int* g_arrive = ctrl + T * NREP;

  const float4* uef = (const float4*)d_in[0];
  const float4* ief = (const float4*)d_in[1];
  float* scores = (float*)d_out;

  hipMemsetAsync(ctrl, 0, ((size_t)T * NREP + 64) * 4, stream);

  lightgcn_fused<<<GRID, 256, 0, stream>>>(
      adj_rows, adj_cols, nnz, T, npw, uef, ief, user_ids, item_ids, U, N, B,
      tcur, g_arrive, bucket, row_ptr, csr, y0b, y1b, y2b, scores);
}

// Round 14
// 270.235 us; speedup vs baseline: 3.6878x; 3.6878x over previous
//
#include <hip/hip_runtime.h>

// LightGCN on MI355X — round 24.
//  * R23 post-mortem: software grid barrier (768 agent-scope fences/barrier
//    across 8 non-coherent XCD L2s) cost ~700us — 10x the launch-gap
//    savings. Fusion refuted; reverted to R21 pipeline (best 265.9us).
//  * spmm_sum: stage width 8->4 (2 stages x 4 gathers = 8 outstanding,
//    live-set ~60 VGPR) + launch_bounds(256,8). Per-SIMD MLP unchanged
//    (8 waves x 8 = 4 x 16); wave concurrency 2x — R19 showed the memory
//    system sustains 4.1 TB/s at 67% occupancy vs 3.3 at 40%.
//    Spill tripwire: WRITE_SIZE must stay ~18.75MB, VGPR <= 64.
//  * partition / build / score byte-identical to R21.
// 6 launches: memset, partition, build+y0, spmm, spmm, score.

#define DIM 64
#define TSHIFT 8
#define TMASK ((1 << TSHIFT) - 1)
#define TPAD 768
#define EWG 6272
#define STAGE_CAP 6272
#define NREP 4
#define RSTR 2560
#define TSTRIDE 10240
#define NI4 7  // ceil((EWG/4)/256) int4 slots per thread

typedef unsigned short u16;
typedef unsigned char u8;
typedef unsigned int u32;
typedef unsigned int uv4 __attribute__((ext_vector_type(4)));
typedef float f2 __attribute__((ext_vector_type(2)));

__device__ __forceinline__ u32 f2bf(float f) {  // RNE pack to bf16 bits
  u32 u = __float_as_uint(f);
  return (u + 0x7FFFu + ((u >> 16) & 1u)) >> 16;
}
__device__ __forceinline__ float bflo(u32 u) {
  return __uint_as_float(u << 16);
}
__device__ __forceinline__ float bfhi(u32 u) {
  return __uint_as_float(u & 0xFFFF0000u);
}
__device__ __forceinline__ f2 up2(u32 u) {
  f2 r;
  r.x = bflo(u);
  r.y = bfhi(u);
  return r;
}

// inclusive scan of lsum across 256 threads; wsum is 4-entry LDS scratch.
__device__ __forceinline__ int block_incl_scan(int lsum, int tid, int* wsum) {
  int lane = tid & 63, wv = tid >> 6;
  int v = lsum;
#pragma unroll
  for (int off = 1; off < 64; off <<= 1) {
    int t = __shfl_up(v, off, 64);
    if (lane >= off) v += t;
  }
  __syncthreads();
  if (lane == 63) wsum[wv] = v;
  __syncthreads();
  int add = 0;
  if (wv > 0) add += wsum[0];
  if (wv > 1) add += wsum[1];
  if (wv > 2) add += wsum[2];
  return v + add;
}

// ---------------- single-pass tile partition into padded bucket ------------

__global__ __launch_bounds__(256) void partition_direct(
    const int* __restrict__ rows, const int* __restrict__ cols, int nnz,
    int T, int* __restrict__ tcur, u32* __restrict__ bucket) {
  __shared__ u32 sorted[STAGE_CAP];
  __shared__ u16 sortedt[STAGE_CAP];
  __shared__ int cnt[TPAD], lstart[TPAD], gbase[TPAD];
  __shared__ int wsum[4];
  int w = blockIdx.x, tid = threadIdx.x;
  int rep = w & (NREP - 1);
  int j0 = tid * 3;
  cnt[j0] = 0; cnt[j0 + 1] = 0; cnt[j0 + 2] = 0;
  __syncthreads();
  int base = w * EWG;
  int end = min(base + EWG, nnz);
  int total = end - base;
  if (total <= 0) return;
  int nv = total >> 2;
  const int4* r4 = (const int4*)(rows + base);
  const int4* c4 = (const int4*)(cols + base);
  // pass 1: histogram rows; cache row int4s in registers for pass 2
  int4 rr[NI4];
#pragma unroll
  for (int j = 0; j < NI4; ++j) {
    int i = tid + j * 256;
    if (i < nv) {
      int4 r = r4[i];
      rr[j] = r;
      atomicAdd(&cnt[r.x >> TSHIFT], 1);
      atomicAdd(&cnt[r.y >> TSHIFT], 1);
      atomicAdd(&cnt[r.z >> TSHIFT], 1);
      atomicAdd(&cnt[r.w >> TSHIFT], 1);
    }
  }
  for (int e = base + (nv << 2) + tid; e < end; e += 256)
    atomicAdd(&cnt[rows[e] >> TSHIFT], 1);
  __syncthreads();
  int c0 = cnt[j0], c1 = cnt[j0 + 1], c2 = cnt[j0 + 2];
  int lsum = c0 + c1 + c2;
  int incl = block_incl_scan(lsum, tid, wsum);
  int excl = incl - lsum;
  lstart[j0] = excl;
  lstart[j0 + 1] = excl + c0;
  lstart[j0 + 2] = excl + c0 + c1;
  if (c0 > 0)
    gbase[j0] = j0 * TSTRIDE + rep * RSTR + atomicAdd(&tcur[j0 * NREP + rep], c0);
  if (c1 > 0)
    gbase[j0 + 1] = (j0 + 1) * TSTRIDE + rep * RSTR +
                    atomicAdd(&tcur[(j0 + 1) * NREP + rep], c1);
  if (c2 > 0)
    gbase[j0 + 2] = (j0 + 2) * TSTRIDE + rep * RSTR +
                    atomicAdd(&tcur[(j0 + 2) * NREP + rep], c2);
  cnt[j0] = 0; cnt[j0 + 1] = 0; cnt[j0 + 2] = 0;
  __syncthreads();
  // pass 2: rows from registers, cols from memory
#pragma unroll
  for (int j = 0; j < NI4; ++j) {
    int i = tid + j * 256;
    if (i < nv) {
      int4 r = rr[j];
      int4 c = c4[i];
      int t, s, d;
      t = r.x >> TSHIFT; s = atomicAdd(&cnt[t], 1); d = lstart[t] + s;
      sorted[d] = ((u32)(r.x & TMASK) << 18) | (u32)c.x; sortedt[d] = (u16)t;
      t = r.y >> TSHIFT; s = atomicAdd(&cnt[t], 1); d = lstart[t] + s;
      sorted[d] = ((u32)(r.y & TMASK) << 18) | (u32)c.y; sortedt[d] = (u16)t;
      t = r.z >> TSHIFT; s = atomicAdd(&cnt[t], 1); d = lstart[t] + s;
      sorted[d] = ((u32)(r.z & TMASK) << 18) | (u32)c.z; sortedt[d] = (u16)t;
      t = r.w >> TSHIFT; s = atomicAdd(&cnt[t], 1); d = lstart[t] + s;
      sorted[d] = ((u32)(r.w & TMASK) << 18) | (u32)c.w; sortedt[d] = (u16)t;
    }
  }
  for (int e = base + (nv << 2) + tid; e < end; e += 256) {
    int r = rows[e];
    int c = cols[e];
    int t = r >> TSHIFT;
    int s = atomicAdd(&cnt[t], 1);
    int d = lstart[t] + s;
    sorted[d] = ((u32)(r & TMASK) << 18) | (u32)c;
    sortedt[d] = (u16)t;
  }
  __syncthreads();
  for (int i = tid; i < total; i += 256) {
    int t = sortedt[i];
    bucket[(size_t)gbase[t] + (i - lstart[t])] = sorted[i];
  }
}

// ---------------- build: one block per 256-row tile, + fused bf16 y0 -------

__global__ __launch_bounds__(256) void build_csr_y0(
    const u32* __restrict__ bucket, const int* __restrict__ tcur, int T,
    int U, int N, const float4* __restrict__ ue, const float4* __restrict__ ie,
    int* __restrict__ row_ptr, u32* __restrict__ csr,
    uint4* __restrict__ y0b) {
  __shared__ int tl[TPAD];
  __shared__ int hist[256];
  __shared__ int cur[256];
  __shared__ int wsum[4];
  int b = blockIdx.x;
  int t = (b & 1) ? (T - 1 - (b >> 1)) : (b >> 1);
  int tid = threadIdx.x;
  int j0 = tid * 3;
  int v0 = 0, v1 = 0, v2 = 0;
  if (j0 < T) {
    int4 q = ((const int4*)tcur)[j0];
    v0 = q.x + q.y + q.z + q.w;
  }
  if (j0 + 1 < T) {
    int4 q = ((const int4*)tcur)[j0 + 1];
    v1 = q.x + q.y + q.z + q.w;
  }
  if (j0 + 2 < T) {
    int4 q = ((const int4*)tcur)[j0 + 2];
    v2 = q.x + q.y + q.z + q.w;
  }
  int lsum = v0 + v1 + v2;
  int incl0 = block_incl_scan(lsum, tid, wsum);
  int excl0 = incl0 - lsum;
  tl[j0] = excl0 + v0;
  tl[j0 + 1] = excl0 + v0 + v1;
  tl[j0 + 2] = excl0 + v0 + v1 + v2;
  hist[tid] = 0;
  __syncthreads();
  int tbase = (t == 0) ? 0 : tl[t - 1];
  int4 rl = ((const int4*)tcur)[t];
#pragma unroll
  for (int rep = 0; rep < NREP; ++rep) {
    int len = (rep == 0) ? rl.x : (rep == 1) ? rl.y : (rep == 2) ? rl.z : rl.w;
    int rs = t * TSTRIDE + rep * RSTR;
    const uint4* b4 = (const uint4*)(bucket + rs);
    int nv = len >> 2;
    for (int i = tid; i < nv; i += 256) {
      uint4 e = b4[i];
      atomicAdd(&hist[e.x >> 18], 1);
      atomicAdd(&hist[e.y >> 18], 1);
      atomicAdd(&hist[e.z >> 18], 1);
      atomicAdd(&hist[e.w >> 18], 1);
    }
    for (int i = rs + (nv << 2) + tid; i < rs + len; i += 256)
      atomicAdd(&hist[bucket[i] >> 18], 1);
  }
  __syncthreads();
  int h = hist[tid];
  int incl = block_incl_scan(h, tid, wsum);
  int r = (t << TSHIFT) + tid;
  if (r < N) row_ptr[r + 1] = tbase + incl;
  if (t == 0 && tid == 0) row_ptr[0] = 0;
  if (b == 0 && tid < 8)  // zero sentinel row of y0b (spmm1 pads with it)
    y0b[(size_t)N * 8 + tid] = make_uint4(0, 0, 0, 0);
  cur[tid] = tbase + incl - h;
  __syncthreads();
  for (int pass = 0; pass < 8; ++pass) {
    int lr = pass * 32 + (tid >> 3);
    int q = tid & 7;
    int row = (t << TSHIFT) + lr;
    if (row < N) {
      float invs = rsqrtf((float)max(hist[lr], 1));
      const float4* src = (row < U) ? (ue + (size_t)row * 16 + q * 2)
                                    : (ie + (size_t)(row - U) * 16 + q * 2);
      float4 a = src[0], bb = src[1];
      uint4 o;
      o.x = f2bf(a.x * invs) | (f2bf(a.y * invs) << 16);
      o.y = f2bf(a.z * invs) | (f2bf(a.w * invs) << 16);
      o.z = f2bf(bb.x * invs) | (f2bf(bb.y * invs) << 16);
      o.w = f2bf(bb.z * invs) | (f2bf(bb.w * invs) << 16);
      y0b[(size_t)row * 8 + q] = o;
    }
  }
#pragma unroll
  for (int rep = 0; rep < NREP; ++rep) {
    int len = (rep == 0) ? rl.x : (rep == 1) ? rl.y : (rep == 2) ? rl.z : rl.w;
    int rs = t * TSTRIDE + rep * RSTR;
    const uint4* b4 = (const uint4*)(bucket + rs);
    int nv = len >> 2;
    for (int i = tid; i < nv; i += 256) {
      uint4 e = b4[i];
      csr[atomicAdd(&cur[e.x >> 18], 1)] = e.x & 0x3FFFFu;
      csr[atomicAdd(&cur[e.y >> 18], 1)] = e.y & 0x3FFFFu;
      csr[atomicAdd(&cur[e.z >> 18], 1)] = e.z & 0x3FFFFu;
      csr[atomicAdd(&cur[e.w >> 18], 1)] = e.w & 0x3FFFFu;
    }
    for (int i = rs + (nv << 2) + tid; i < rs + len; i += 256) {
      u32 e = bucket[i];
      csr[atomicAdd(&cur[e >> 18], 1)] = e & 0x3FFFFu;
    }
  }
}

// ---------------- SpMM: 1 row / 8-lane group, 2-stage x 4-gather pipeline --

__device__ __forceinline__ void load_stage4(
    u32 (&c)[4], uv4 (&g)[4], int k, int d, int s,
    const u32* __restrict__ csr, const char* __restrict__ yb, u32 soff,
    int n) {
#pragma unroll
  for (int j = 0; j < 4; ++j) c[j] = (k + j < d) ? csr[s + k + j] : (u32)n;
#pragma unroll
  for (int j = 0; j < 4; ++j)
    g[j] = *(const uv4*)(yb + (size_t)(((size_t)c[j] << 7) | soff));
}

#define ACC_STAGE4(G)                                                        \
  _Pragma("unroll") for (int j = 0; j < 4; ++j) {                            \
    a0 += up2(G[j].x);                                                       \
    a1 += up2(G[j].y);                                                       \
    a2 += up2(G[j].z);                                                       \
    a3 += up2(G[j].w);                                                       \
  }

__global__ __launch_bounds__(256, 8) void spmm_sum(
    const int* __restrict__ row_ptr, const u32* __restrict__ csr,
    const u16* __restrict__ yin, u16* __restrict__ yout, int n) {
  if (blockIdx.x == 0 && threadIdx.x < 8)  // zero sentinel row of output
    ((uint4*)(yout + (size_t)n * DIM))[threadIdx.x] = make_uint4(0, 0, 0, 0);
  int row = (blockIdx.x * 256 + threadIdx.x) >> 3;
  int q8 = threadIdx.x & 7;
  if (row >= n) return;
  int s = row_ptr[row];
  int d = row_ptr[row + 1] - s;
  const char* yb = (const char*)yin;
  u32 soff = (u32)q8 << 4;
  f2 a0 = 0.f, a1 = 0.f, a2 = 0.f, a3 = 0.f;
  u32 cA[4], cB[4];
  uv4 gA[4], gB[4];
  if (d > 0) {
    load_stage4(cA, gA, 0, d, s, csr, yb, soff, n);
    int k = 4;
    while (k < d) {
      load_stage4(cB, gB, k, d, s, csr, yb, soff, n);
      k += 4;
      ACC_STAGE4(gA)
      if (k >= d) {
        ACC_STAGE4(gB)
        goto done;
      }
      load_stage4(cA, gA, k, d, s, csr, yb, soff, n);
      k += 4;
      ACC_STAGE4(gB)
    }
    ACC_STAGE4(gA)
  }
done:;
  float inv = 1.0f / (float)max(d, 1);
  uint4 o;
  o.x = f2bf(a0.x * inv) | (f2bf(a0.y * inv) << 16);
  o.y = f2bf(a1.x * inv) | (f2bf(a1.y * inv) << 16);
  o.z = f2bf(a2.x * inv) | (f2bf(a2.y * inv) << 16);
  o.w = f2bf(a3.x * inv) | (f2bf(a3.y * inv) << 16);
  ((uint4*)(yout + (size_t)row * DIM))[q8] = o;
}

// ---------------- fused layer-3 + scorer (R21 one-wave-per-gather) ---------

#define ACC8(G)                                                              \
  s0 += bflo(G.x); s1 += bfhi(G.x);                                          \
  s2 += bflo(G.y); s3 += bfhi(G.y);                                          \
  s4 += bflo(G.z); s5 += bfhi(G.z);                                          \
  s6 += bflo(G.w); s7 += bfhi(G.w);

__device__ __forceinline__ void gather8(
    const int* __restrict__ row_ptr, const u32* __restrict__ csr,
    const u16* __restrict__ y, int row, int s, int q8, int n, float* o) {
  int start = row_ptr[row];
  int end = row_ptr[row + 1];
  float s0 = 0.f, s1 = 0.f, s2 = 0.f, s3 = 0.f;
  float s4 = 0.f, s5 = 0.f, s6 = 0.f, s7 = 0.f;
  for (int k = start + s; k < end; k += 16) {
    int k2 = k + 8;
    bool ok2 = k2 < end;
    u32 c0 = csr[k];
    u32 c1 = ok2 ? csr[k2] : (u32)n;
    uint4 g0 = ((const uint4*)(y + (size_t)c0 * DIM))[q8];
    uint4 g1 = ((const uint4*)(y + (size_t)c1 * DIM))[q8];
    ACC8(g0) ACC8(g1)
  }
  for (int m = 8; m <= 32; m <<= 1) {
    s0 += __shfl_xor(s0, m, 64); s1 += __shfl_xor(s1, m, 64);
    s2 += __shfl_xor(s2, m, 64); s3 += __shfl_xor(s3, m, 64);
    s4 += __shfl_xor(s4, m, 64); s5 += __shfl_xor(s5, m, 64);
    s6 += __shfl_xor(s6, m, 64); s7 += __shfl_xor(s7, m, 64);
  }
  o[0] = s0; o[1] = s1; o[2] = s2; o[3] = s3;
  o[4] = s4; o[5] = s5; o[6] = s6; o[7] = s7;
}

// 2 pairs/block; 2 waves/pair (wave0=user row, wave1=item row). Each wave
// builds its side's full 64-dim vector into LDS; wave0 does the dot.
__global__ __launch_bounds__(256) void spmm3_score(
    const int* __restrict__ row_ptr, const u32* __restrict__ csr,
    const float* __restrict__ ue, const float* __restrict__ ie,
    const u16* __restrict__ y1b, const u16* __restrict__ y2b,
    const int* __restrict__ user_ids, const int* __restrict__ item_ids,
    int U, int N, int batch, float* __restrict__ out) {
  __shared__ float ab[2][2][64];  // [pair-in-block][side][dim]
  int tid = threadIdx.x;
  int pl = tid >> 7;              // pair slot in block (0,1)
  int side = (tid >> 6) & 1;      // 0=user, 1=item
  int lane = tid & 63;
  int w = blockIdx.x * 2 + pl;
  bool active = w < batch;
  int s = lane >> 3;
  int q8 = lane & 7;
  if (active) {
    int u = user_ids[w];
    int iti = item_ids[w];
    int row = (side == 0) ? u : iti + U;
    float g[8];
    gather8(row_ptr, csr, y2b, row, s, q8, N, g);
    int dd = row_ptr[row + 1] - row_ptr[row];
    float sd = sqrtf((float)max(dd, 1)), rd = 1.0f / sd;
    const float4* pe = (side == 0)
                           ? (const float4*)(ue + (size_t)u * DIM) + q8 * 2
                           : (const float4*)(ie + (size_t)iti * DIM) + q8 * 2;
    float4 ea = pe[0], eb = pe[1];
    uint4 y1v = ((const uint4*)(y1b + (size_t)row * DIM))[q8];
    uint4 y2v = ((const uint4*)(y2b + (size_t)row * DIM))[q8];
    if (s == 0) {  // one writer per q8 (all s-lanes hold identical g)
      float* dst = &ab[pl][side][q8 * 8];
      dst[0] = ea.x + sd * (bflo(y1v.x) + bflo(y2v.x)) + rd * g[0];
      dst[1] = ea.y + sd * (bfhi(y1v.x) + bfhi(y2v.x)) + rd * g[1];
      dst[2] = ea.z + sd * (bflo(y1v.y) + bflo(y2v.y)) + rd * g[2];
      dst[3] = ea.w + sd * (bfhi(y1v.y) + bfhi(y2v.y)) + rd * g[3];
      dst[4] = eb.x + sd * (bflo(y1v.z) + bflo(y2v.z)) + rd * g[4];
      dst[5] = eb.y + sd * (bfhi(y1v.z) + bfhi(y2v.z)) + rd * g[5];
      dst[6] = eb.z + sd * (bflo(y1v.w) + bflo(y2v.w)) + rd * g[6];
      dst[7] = eb.w + sd * (bfhi(y1v.w) + bfhi(y2v.w)) + rd * g[7];
    }
  }
  __syncthreads();
  if (active && side == 0) {
    float p = ab[pl][0][lane] * ab[pl][1][lane];
    p += __shfl_xor(p, 1, 64);
    p += __shfl_xor(p, 2, 64);
    p += __shfl_xor(p, 4, 64);
    p += __shfl_xor(p, 8, 64);
    p += __shfl_xor(p, 16, 64);
    p += __shfl_xor(p, 32, 64);
    if (lane == 0) out[w] = p * (1.0f / 16.0f);
  }
}

extern "C" void kernel_launch(void* const* d_in, const int* in_sizes, int n_in,
                              void* d_out, int out_size, void* d_ws, size_t ws_size,
                              hipStream_t stream) {
  const float* user_emb = (const float*)d_in[0];
  const float* item_emb = (const float*)d_in[1];
  const int* adj_rows = (const int*)d_in[3];
  const int* adj_cols = (const int*)d_in[4];
  const int* user_ids = (const int*)d_in[5];
  const int* item_ids = (const int*)d_in[6];
  float* scores = (float*)d_out;

  const int U = in_sizes[0] / DIM;  // 100000
  const int I = in_sizes[1] / DIM;  // 50000
  const int N = U + I;              // 150000
  const int nnz = in_sizes[2];      // 3200000
  const int B = in_sizes[5];        // 4096

  const int T = (N + TMASK) >> TSHIFT;    // 586
  const int npw = (nnz + EWG - 1) / EWG;  // 511

  char* p = (char*)d_ws;
  auto carve = [&](size_t bytes) {
    void* r = (void*)p;
    p += (bytes + 255) & ~(size_t)255;
    return r;
  };
  u16* y0b = (u16*)carve((size_t)(N + 1) * DIM * 2);
  u16* y1b = (u16*)carve((size_t)(N + 1) * DIM * 2);
  u16* y2b = (u16*)carve((size_t)(N + 1) * DIM * 2);
  int* row_ptr = (int*)carve((size_t)(N + 1) * 4);
  int* tcur = (int*)carve((size_t)T * NREP * 4);
  u32* bucket = (u32*)carve((size_t)(T + 1) * TSTRIDE * 4);
  u32* csr = (u32*)carve((size_t)nnz * 4);

  hipMemsetAsync(tcur, 0, (size_t)T * NREP * 4, stream);

  partition_direct<<<npw, 256, 0, stream>>>(adj_rows, adj_cols, nnz, T, tcur,
                                            bucket);

  build_csr_y0<<<T, 256, 0, stream>>>(bucket, tcur, T, U, N,
                                      (const float4*)user_emb,
                                      (const float4*)item_emb, row_ptr,
                                      csr, (uint4*)y0b);

  const int sblocks = (N * 8 + 255) / 256;  // 8 lanes per row
  spmm_sum<<<sblocks, 256, 0, stream>>>(row_ptr, csr, y0b, y1b, N);
  spmm_sum<<<sblocks, 256, 0, stream>>>(row_ptr, csr, y1b, y2b, N);

  spmm3_score<<<(B + 1) / 2, 256, 0, stream>>>(row_ptr, csr, user_emb,
                                               item_emb, y1b, y2b, user_ids,
                                               item_ids, U, N, B, scores);
}

// Round 15
// 262.739 us; speedup vs baseline: 3.7930x; 1.0285x over previous
//
#include <hip/hip_runtime.h>

// LightGCN on MI355X — round 25.
//  * R24 null result: occupancy 40->58% at SAME dur/BW -> spmm is bound by
//    HBM random-sector efficiency at the compulsory fetch floor (134MB,
//    8-XCD replication), not latency. spmm reverted to R21 8-wide
//    (47.7us, FETCH 134 < R24's 139).
//  * build_csr_y0: tile's bucket entries cached in LDS during the
//    histogram pass (<=10240 entries, 40KB; 46KB total -> 3 blocks/CU,
//    all 586 blocks resident); scatter pass reads LDS instead of a second
//    global (L3-latency) pass over 12.8MB.
//  * partition / score byte-identical to R21.
// 6 launches: memset, partition, build+y0, spmm, spmm, score.

#define DIM 64
#define TSHIFT 8
#define TMASK ((1 << TSHIFT) - 1)
#define TPAD 768
#define EWG 6272
#define STAGE_CAP 6272
#define NREP 4
#define RSTR 2560
#define TSTRIDE 10240
#define NI4 7  // ceil((EWG/4)/256) int4 slots per thread

typedef unsigned short u16;
typedef unsigned char u8;
typedef unsigned int u32;
typedef unsigned int uv4 __attribute__((ext_vector_type(4)));
typedef float f2 __attribute__((ext_vector_type(2)));

__device__ __forceinline__ u32 f2bf(float f) {  // RNE pack to bf16 bits
  u32 u = __float_as_uint(f);
  return (u + 0x7FFFu + ((u >> 16) & 1u)) >> 16;
}
__device__ __forceinline__ float bflo(u32 u) {
  return __uint_as_float(u << 16);
}
__device__ __forceinline__ float bfhi(u32 u) {
  return __uint_as_float(u & 0xFFFF0000u);
}
__device__ __forceinline__ f2 up2(u32 u) {
  f2 r;
  r.x = bflo(u);
  r.y = bfhi(u);
  return r;
}

// inclusive scan of lsum across 256 threads; wsum is 4-entry LDS scratch.
__device__ __forceinline__ int block_incl_scan(int lsum, int tid, int* wsum) {
  int lane = tid & 63, wv = tid >> 6;
  int v = lsum;
#pragma unroll
  for (int off = 1; off < 64; off <<= 1) {
    int t = __shfl_up(v, off, 64);
    if (lane >= off) v += t;
  }
  __syncthreads();
  if (lane == 63) wsum[wv] = v;
  __syncthreads();
  int add = 0;
  if (wv > 0) add += wsum[0];
  if (wv > 1) add += wsum[1];
  if (wv > 2) add += wsum[2];
  return v + add;
}

// ---------------- single-pass tile partition into padded bucket ------------

__global__ __launch_bounds__(256) void partition_direct(
    const int* __restrict__ rows, const int* __restrict__ cols, int nnz,
    int T, int* __restrict__ tcur, u32* __restrict__ bucket) {
  __shared__ u32 sorted[STAGE_CAP];
  __shared__ u16 sortedt[STAGE_CAP];
  __shared__ int cnt[TPAD], lstart[TPAD], gbase[TPAD];
  __shared__ int wsum[4];
  int w = blockIdx.x, tid = threadIdx.x;
  int rep = w & (NREP - 1);
  int j0 = tid * 3;
  cnt[j0] = 0; cnt[j0 + 1] = 0; cnt[j0 + 2] = 0;
  __syncthreads();
  int base = w * EWG;
  int end = min(base + EWG, nnz);
  int total = end - base;
  if (total <= 0) return;
  int nv = total >> 2;
  const int4* r4 = (const int4*)(rows + base);
  const int4* c4 = (const int4*)(cols + base);
  // pass 1: histogram rows; cache row int4s in registers for pass 2
  int4 rr[NI4];
#pragma unroll
  for (int j = 0; j < NI4; ++j) {
    int i = tid + j * 256;
    if (i < nv) {
      int4 r = r4[i];
      rr[j] = r;
      atomicAdd(&cnt[r.x >> TSHIFT], 1);
      atomicAdd(&cnt[r.y >> TSHIFT], 1);
      atomicAdd(&cnt[r.z >> TSHIFT], 1);
      atomicAdd(&cnt[r.w >> TSHIFT], 1);
    }
  }
  for (int e = base + (nv << 2) + tid; e < end; e += 256)
    atomicAdd(&cnt[rows[e] >> TSHIFT], 1);
  __syncthreads();
  int c0 = cnt[j0], c1 = cnt[j0 + 1], c2 = cnt[j0 + 2];
  int lsum = c0 + c1 + c2;
  int incl = block_incl_scan(lsum, tid, wsum);
  int excl = incl - lsum;
  lstart[j0] = excl;
  lstart[j0 + 1] = excl + c0;
  lstart[j0 + 2] = excl + c0 + c1;
  if (c0 > 0)
    gbase[j0] = j0 * TSTRIDE + rep * RSTR + atomicAdd(&tcur[j0 * NREP + rep], c0);
  if (c1 > 0)
    gbase[j0 + 1] = (j0 + 1) * TSTRIDE + rep * RSTR +
                    atomicAdd(&tcur[(j0 + 1) * NREP + rep], c1);
  if (c2 > 0)
    gbase[j0 + 2] = (j0 + 2) * TSTRIDE + rep * RSTR +
                    atomicAdd(&tcur[(j0 + 2) * NREP + rep], c2);
  cnt[j0] = 0; cnt[j0 + 1] = 0; cnt[j0 + 2] = 0;
  __syncthreads();
  // pass 2: rows from registers, cols from memory
#pragma unroll
  for (int j = 0; j < NI4; ++j) {
    int i = tid + j * 256;
    if (i < nv) {
      int4 r = rr[j];
      int4 c = c4[i];
      int t, s, d;
      t = r.x >> TSHIFT; s = atomicAdd(&cnt[t], 1); d = lstart[t] + s;
      sorted[d] = ((u32)(r.x & TMASK) << 18) | (u32)c.x; sortedt[d] = (u16)t;
      t = r.y >> TSHIFT; s = atomicAdd(&cnt[t], 1); d = lstart[t] + s;
      sorted[d] = ((u32)(r.y & TMASK) << 18) | (u32)c.y; sortedt[d] = (u16)t;
      t = r.z >> TSHIFT; s = atomicAdd(&cnt[t], 1); d = lstart[t] + s;
      sorted[d] = ((u32)(r.z & TMASK) << 18) | (u32)c.z; sortedt[d] = (u16)t;
      t = r.w >> TSHIFT; s = atomicAdd(&cnt[t], 1); d = lstart[t] + s;
      sorted[d] = ((u32)(r.w & TMASK) << 18) | (u32)c.w; sortedt[d] = (u16)t;
    }
  }
  for (int e = base + (nv << 2) + tid; e < end; e += 256) {
    int r = rows[e];
    int c = cols[e];
    int t = r >> TSHIFT;
    int s = atomicAdd(&cnt[t], 1);
    int d = lstart[t] + s;
    sorted[d] = ((u32)(r & TMASK) << 18) | (u32)c;
    sortedt[d] = (u16)t;
  }
  __syncthreads();
  for (int i = tid; i < total; i += 256) {
    int t = sortedt[i];
    bucket[(size_t)gbase[t] + (i - lstart[t])] = sorted[i];
  }
}

// ---------------- build: one block per 256-row tile, LDS-cached bucket -----

__global__ __launch_bounds__(256) void build_csr_y0(
    const u32* __restrict__ bucket, const int* __restrict__ tcur, int T,
    int U, int N, const float4* __restrict__ ue, const float4* __restrict__ ie,
    int* __restrict__ row_ptr, u32* __restrict__ csr,
    uint4* __restrict__ y0b) {
  __shared__ u32 ebuf[TSTRIDE];  // tile entries, compacted (<= 10240)
  __shared__ int tl[TPAD];
  __shared__ int hist[256];
  __shared__ int cur[256];
  __shared__ int wsum[4];
  int b = blockIdx.x;
  int t = (b & 1) ? (T - 1 - (b >> 1)) : (b >> 1);
  int tid = threadIdx.x;
  int j0 = tid * 3;
  int v0 = 0, v1 = 0, v2 = 0;
  if (j0 < T) {
    int4 q = ((const int4*)tcur)[j0];
    v0 = q.x + q.y + q.z + q.w;
  }
  if (j0 + 1 < T) {
    int4 q = ((const int4*)tcur)[j0 + 1];
    v1 = q.x + q.y + q.z + q.w;
  }
  if (j0 + 2 < T) {
    int4 q = ((const int4*)tcur)[j0 + 2];
    v2 = q.x + q.y + q.z + q.w;
  }
  int lsum = v0 + v1 + v2;
  int incl0 = block_incl_scan(lsum, tid, wsum);
  int excl0 = incl0 - lsum;
  tl[j0] = excl0 + v0;
  tl[j0 + 1] = excl0 + v0 + v1;
  tl[j0 + 2] = excl0 + v0 + v1 + v2;
  hist[tid] = 0;
  __syncthreads();
  int tbase = (t == 0) ? 0 : tl[t - 1];
  int4 rl = ((const int4*)tcur)[t];
  // single global pass: histogram + compact tile into LDS ebuf
  int off = 0;
#pragma unroll
  for (int rep = 0; rep < NREP; ++rep) {
    int len = (rep == 0) ? rl.x : (rep == 1) ? rl.y : (rep == 2) ? rl.z : rl.w;
    int rs = t * TSTRIDE + rep * RSTR;
    const uint4* b4 = (const uint4*)(bucket + rs);
    int nv = len >> 2;
    for (int i = tid; i < nv; i += 256) {
      uint4 e = b4[i];
      int d = off + (i << 2);
      ebuf[d] = e.x; ebuf[d + 1] = e.y; ebuf[d + 2] = e.z; ebuf[d + 3] = e.w;
      atomicAdd(&hist[e.x >> 18], 1);
      atomicAdd(&hist[e.y >> 18], 1);
      atomicAdd(&hist[e.z >> 18], 1);
      atomicAdd(&hist[e.w >> 18], 1);
    }
    for (int i = (nv << 2) + tid; i < len; i += 256) {
      u32 e = bucket[rs + i];
      ebuf[off + i] = e;
      atomicAdd(&hist[e >> 18], 1);
    }
    off += len;
  }
  int tlen = off;
  __syncthreads();
  int h = hist[tid];
  int incl = block_incl_scan(h, tid, wsum);
  int r = (t << TSHIFT) + tid;
  if (r < N) row_ptr[r + 1] = tbase + incl;
  if (t == 0 && tid == 0) row_ptr[0] = 0;
  if (b == 0 && tid < 8)  // zero sentinel row of y0b (spmm1 pads with it)
    y0b[(size_t)N * 8 + tid] = make_uint4(0, 0, 0, 0);
  cur[tid] = tbase + incl - h;
  __syncthreads();
  for (int pass = 0; pass < 8; ++pass) {
    int lr = pass * 32 + (tid >> 3);
    int q = tid & 7;
    int row = (t << TSHIFT) + lr;
    if (row < N) {
      float invs = rsqrtf((float)max(hist[lr], 1));
      const float4* src = (row < U) ? (ue + (size_t)row * 16 + q * 2)
                                    : (ie + (size_t)(row - U) * 16 + q * 2);
      float4 a = src[0], bb = src[1];
      uint4 o;
      o.x = f2bf(a.x * invs) | (f2bf(a.y * invs) << 16);
      o.y = f2bf(a.z * invs) | (f2bf(a.w * invs) << 16);
      o.z = f2bf(bb.x * invs) | (f2bf(bb.y * invs) << 16);
      o.w = f2bf(bb.z * invs) | (f2bf(bb.w * invs) << 16);
      y0b[(size_t)row * 8 + q] = o;
    }
  }
  // scatter entries into compact csr, from LDS
  for (int i = tid; i < tlen; i += 256) {
    u32 e = ebuf[i];
    csr[atomicAdd(&cur[e >> 18], 1)] = e & 0x3FFFFu;
  }
}

// ---------------- SpMM: 1 row / 8-lane group, 2-stage pipelined gathers ----

__device__ __forceinline__ void load_stage(
    u32 (&c)[8], uv4 (&g)[8], int k, int d, int s,
    const u32* __restrict__ csr, const char* __restrict__ yb, u32 soff,
    int n) {
#pragma unroll
  for (int j = 0; j < 8; ++j) c[j] = (k + j < d) ? csr[s + k + j] : (u32)n;
#pragma unroll
  for (int j = 0; j < 8; ++j)
    g[j] = *(const uv4*)(yb + (size_t)(((size_t)c[j] << 7) | soff));
}

#define ACC_STAGE(G)                                                         \
  _Pragma("unroll") for (int j = 0; j < 8; ++j) {                            \
    a0 += up2(G[j].x);                                                       \
    a1 += up2(G[j].y);                                                       \
    a2 += up2(G[j].z);                                                       \
    a3 += up2(G[j].w);                                                       \
  }

__global__ __launch_bounds__(256, 4) void spmm_sum(
    const int* __restrict__ row_ptr, const u32* __restrict__ csr,
    const u16* __restrict__ yin, u16* __restrict__ yout, int n) {
  if (blockIdx.x == 0 && threadIdx.x < 8)  // zero sentinel row of output
    ((uint4*)(yout + (size_t)n * DIM))[threadIdx.x] = make_uint4(0, 0, 0, 0);
  int row = (blockIdx.x * 256 + threadIdx.x) >> 3;
  int q8 = threadIdx.x & 7;
  if (row >= n) return;
  int s = row_ptr[row];
  int d = row_ptr[row + 1] - s;
  const char* yb = (const char*)yin;
  u32 soff = (u32)q8 << 4;
  f2 a0 = 0.f, a1 = 0.f, a2 = 0.f, a3 = 0.f;
  u32 cA[8], cB[8];
  uv4 gA[8], gB[8];
  if (d > 0) {
    load_stage(cA, gA, 0, d, s, csr, yb, soff, n);
    int k = 8;
    while (k < d) {
      load_stage(cB, gB, k, d, s, csr, yb, soff, n);
      k += 8;
      ACC_STAGE(gA)
      if (k >= d) {
        ACC_STAGE(gB)
        goto done;
      }
      load_stage(cA, gA, k, d, s, csr, yb, soff, n);
      k += 8;
      ACC_STAGE(gB)
    }
    ACC_STAGE(gA)
  }
done:;
  float inv = 1.0f / (float)max(d, 1);
  uint4 o;
  o.x = f2bf(a0.x * inv) | (f2bf(a0.y * inv) << 16);
  o.y = f2bf(a1.x * inv) | (f2bf(a1.y * inv) << 16);
  o.z = f2bf(a2.x * inv) | (f2bf(a2.y * inv) << 16);
  o.w = f2bf(a3.x * inv) | (f2bf(a3.y * inv) << 16);
  ((uint4*)(yout + (size_t)row * DIM))[q8] = o;
}

// ---------------- fused layer-3 + scorer (R21 one-wave-per-gather) ---------

#define ACC8(G)                                                              \
  s0 += bflo(G.x); s1 += bfhi(G.x);                                          \
  s2 += bflo(G.y); s3 += bfhi(G.y);                                          \
  s4 += bflo(G.z); s5 += bfhi(G.z);                                          \
  s6 += bflo(G.w); s7 += bfhi(G.w);

__device__ __forceinline__ void gather8(
    const int* __restrict__ row_ptr, const u32* __restrict__ csr,
    const u16* __restrict__ y, int row, int s, int q8, int n, float* o) {
  int start = row_ptr[row];
  int end = row_ptr[row + 1];
  float s0 = 0.f, s1 = 0.f, s2 = 0.f, s3 = 0.f;
  float s4 = 0.f, s5 = 0.f, s6 = 0.f, s7 = 0.f;
  for (int k = start + s; k < end; k += 16) {
    int k2 = k + 8;
    bool ok2 = k2 < end;
    u32 c0 = csr[k];
    u32 c1 = ok2 ? csr[k2] : (u32)n;
    uint4 g0 = ((const uint4*)(y + (size_t)c0 * DIM))[q8];
    uint4 g1 = ((const uint4*)(y + (size_t)c1 * DIM))[q8];
    ACC8(g0) ACC8(g1)
  }
  for (int m = 8; m <= 32; m <<= 1) {
    s0 += __shfl_xor(s0, m, 64); s1 += __shfl_xor(s1, m, 64);
    s2 += __shfl_xor(s2, m, 64); s3 += __shfl_xor(s3, m, 64);
    s4 += __shfl_xor(s4, m, 64); s5 += __shfl_xor(s5, m, 64);
    s6 += __shfl_xor(s6, m, 64); s7 += __shfl_xor(s7, m, 64);
  }
  o[0] = s0; o[1] = s1; o[2] = s2; o[3] = s3;
  o[4] = s4; o[5] = s5; o[6] = s6; o[7] = s7;
}

// 2 pairs/block; 2 waves/pair (wave0=user row, wave1=item row). Each wave
// builds its side's full 64-dim vector into LDS; wave0 does the dot.
__global__ __launch_bounds__(256) void spmm3_score(
    const int* __restrict__ row_ptr, const u32* __restrict__ csr,
    const float* __restrict__ ue, const float* __restrict__ ie,
    const u16* __restrict__ y1b, const u16* __restrict__ y2b,
    const int* __restrict__ user_ids, const int* __restrict__ item_ids,
    int U, int N, int batch, float* __restrict__ out) {
  __shared__ float ab[2][2][64];  // [pair-in-block][side][dim]
  int tid = threadIdx.x;
  int pl = tid >> 7;              // pair slot in block (0,1)
  int side = (tid >> 6) & 1;      // 0=user, 1=item
  int lane = tid & 63;
  int w = blockIdx.x * 2 + pl;
  bool active = w < batch;
  int s = lane >> 3;
  int q8 = lane & 7;
  if (active) {
    int u = user_ids[w];
    int iti = item_ids[w];
    int row = (side == 0) ? u : iti + U;
    float g[8];
    gather8(row_ptr, csr, y2b, row, s, q8, N, g);
    int dd = row_ptr[row + 1] - row_ptr[row];
    float sd = sqrtf((float)max(dd, 1)), rd = 1.0f / sd;
    const float4* pe = (side == 0)
                           ? (const float4*)(ue + (size_t)u * DIM) + q8 * 2
                           : (const float4*)(ie + (size_t)iti * DIM) + q8 * 2;
    float4 ea = pe[0], eb = pe[1];
    uint4 y1v = ((const uint4*)(y1b + (size_t)row * DIM))[q8];
    uint4 y2v = ((const uint4*)(y2b + (size_t)row * DIM))[q8];
    if (s == 0) {  // one writer per q8 (all s-lanes hold identical g)
      float* dst = &ab[pl][side][q8 * 8];
      dst[0] = ea.x + sd * (bflo(y1v.x) + bflo(y2v.x)) + rd * g[0];
      dst[1] = ea.y + sd * (bfhi(y1v.x) + bfhi(y2v.x)) + rd * g[1];
      dst[2] = ea.z + sd * (bflo(y1v.y) + bflo(y2v.y)) + rd * g[2];
      dst[3] = ea.w + sd * (bfhi(y1v.y) + bfhi(y2v.y)) + rd * g[3];
      dst[4] = eb.x + sd * (bflo(y1v.z) + bflo(y2v.z)) + rd * g[4];
      dst[5] = eb.y + sd * (bfhi(y1v.z) + bfhi(y2v.z)) + rd * g[5];
      dst[6] = eb.z + sd * (bflo(y1v.w) + bflo(y2v.w)) + rd * g[6];
      dst[7] = eb.w + sd * (bfhi(y1v.w) + bfhi(y2v.w)) + rd * g[7];
    }
  }
  __syncthreads();
  if (active && side == 0) {
    float p = ab[pl][0][lane] * ab[pl][1][lane];
    p += __shfl_xor(p, 1, 64);
    p += __shfl_xor(p, 2, 64);
    p += __shfl_xor(p, 4, 64);
    p += __shfl_xor(p, 8, 64);
    p += __shfl_xor(p, 16, 64);
    p += __shfl_xor(p, 32, 64);
    if (lane == 0) out[w] = p * (1.0f / 16.0f);
  }
}

extern "C" void kernel_launch(void* const* d_in, const int* in_sizes, int n_in,
                              void* d_out, int out_size, void* d_ws, size_t ws_size,
                              hipStream_t stream) {
  const float* user_emb = (const float*)d_in[0];
  const float* item_emb = (const float*)d_in[1];
  const int* adj_rows = (const int*)d_in[3];
  const int* adj_cols = (const int*)d_in[4];
  const int* user_ids = (const int*)d_in[5];
  const int* item_ids = (const int*)d_in[6];
  float* scores = (float*)d_out;

  const int U = in_sizes[0] / DIM;  // 100000
  const int I = in_sizes[1] / DIM;  // 50000
  const int N = U + I;              // 150000
  const int nnz = in_sizes[2];      // 3200000
  const int B = in_sizes[5];        // 4096

  const int T = (N + TMASK) >> TSHIFT;    // 586
  const int npw = (nnz + EWG - 1) / EWG;  // 511

  char* p = (char*)d_ws;
  auto carve = [&](size_t bytes) {
    void* r = (void*)p;
    p += (bytes + 255) & ~(size_t)255;
    return r;
  };
  u16* y0b = (u16*)carve((size_t)(N + 1) * DIM * 2);
  u16* y1b = (u16*)carve((size_t)(N + 1) * DIM * 2);
  u16* y2b = (u16*)carve((size_t)(N + 1) * DIM * 2);
  int* row_ptr = (int*)carve((size_t)(N + 1) * 4);
  int* tcur = (int*)carve((size_t)T * NREP * 4);
  u32* bucket = (u32*)carve((size_t)(T + 1) * TSTRIDE * 4);
  u32* csr = (u32*)carve((size_t)nnz * 4);

  hipMemsetAsync(tcur, 0, (size_t)T * NREP * 4, stream);

  partition_direct<<<npw, 256, 0, stream>>>(adj_rows, adj_cols, nnz, T, tcur,
                                            bucket);

  build_csr_y0<<<T, 256, 0, stream>>>(bucket, tcur, T, U, N,
                                      (const float4*)user_emb,
                                      (const float4*)item_emb, row_ptr,
                                      csr, (uint4*)y0b);

  const int sblocks = (N * 8 + 255) / 256;  // 8 lanes per row
  spmm_sum<<<sblocks, 256, 0, stream>>>(row_ptr, csr, y0b, y1b, N);
  spmm_sum<<<sblocks, 256, 0, stream>>>(row_ptr, csr, y1b, y2b, N);

  spmm3_score<<<(B + 1) / 2, 256, 0, stream>>>(row_ptr, csr, user_emb,
                                               item_emb, y1b, y2b, user_ids,
                                               item_ids, U, N, B, scores);
}